// Round 4
// baseline (487.929 us; speedup 1.0000x reference)
//
#include <hip/hip_runtime.h>

#define NB 256
#define NT 512
#define NI 64
#define NH 256
#define NO 16
#define GB 16           // batches per block
#define NBLK (NB / GB)  // 16 blocks

typedef __attribute__((ext_vector_type(8))) short short8;
typedef __attribute__((ext_vector_type(8))) __bf16 bf16x8;
typedef __attribute__((ext_vector_type(4))) float f32x4;
typedef __attribute__((ext_vector_type(2))) unsigned int uint2v;

__device__ __forceinline__ unsigned short f2bf(float f) {
  unsigned u = __builtin_bit_cast(unsigned, f);
  u += 0x7fffu + ((u >> 16) & 1u);          // round-to-nearest-even
  return (unsigned short)(u >> 16);
}

// D = A*B + C ; A = weights [16m x 32k], B = activations [32k x 16n]
__device__ __forceinline__ f32x4 mfma16(short8 a, short8 b, f32x4 c) {
  return __builtin_amdgcn_mfma_f32_16x16x32_bf16(
      __builtin_bit_cast(bf16x8, a), __builtin_bit_cast(bf16x8, b), c, 0, 0, 0);
}

__device__ __forceinline__ short8 pack8(const float* __restrict__ p) {
  f32x4 lo = *reinterpret_cast<const f32x4*>(p);
  f32x4 hi = *reinterpret_cast<const f32x4*>(p + 4);
  short8 r;
#pragma unroll
  for (int i = 0; i < 4; ++i) {
    r[i]     = (short)f2bf(lo[i]);
    r[i + 4] = (short)f2bf(hi[i]);
  }
  return r;
}

__device__ __forceinline__ uint2v packbf4(f32x4 v) {
  uint2v d;
  d.x = (unsigned)f2bf(v[0]) | ((unsigned)f2bf(v[1]) << 16);
  d.y = (unsigned)f2bf(v[2]) | ((unsigned)f2bf(v[3]) << 16);
  return d;
}

// LDS-only barrier: drain DS ops, sync; global loads/stores stay in flight.
__device__ __forceinline__ void step_barrier() {
  asm volatile("s_waitcnt lgkmcnt(0)" ::: "memory");
  __builtin_amdgcn_s_barrier();
  asm volatile("" ::: "memory");
}

// 16 blocks, 16 batches each. 256 threads = 4 waves; wave w owns j in
// [w*64, w*64+64). Activation fragments live in LDS in MFMA B-layout:
// frag[buf][kt][row=n+16*kgrp][e], k = kt*32 + kgrp*8 + e (k<256: h, k>=256: x).
// Rows are XOR-swizzled (r^(r>>3)) against the stride-16B bank conflict.
__global__ __launch_bounds__(256, 1)
void rnn_fused(const float* __restrict__ x,  const float* __restrict__ Wi,
               const float* __restrict__ bi, const float* __restrict__ Wh,
               const float* __restrict__ bh, const float* __restrict__ Wo,
               const float* __restrict__ bo, const float* __restrict__ h0,
               float* __restrict__ dout)
{
  const int b0  = blockIdx.x * GB;
  const int tid = threadIdx.x;
  const int w   = tid >> 6;   // wave 0..3
  const int l   = tid & 63;   // lane
  const int g   = l >> 4;     // 16-lane group
  const int c   = l & 15;     // index within group

  __shared__ __align__(16) unsigned short frag[2][10][64][8]; // 20 KB
  char* fragc = (char*)frag;

  float* outp = dout;                              // [B,T,O]
  float* hidp = dout + (size_t)NB * NT * NO;       // [B,H]
  float* rnnp = hidp + (size_t)NB * NH;            // [B,T,H]

  const f32x4 cz = {0.f, 0.f, 0.f, 0.f};

  // ---- weight A-fragments: A[m][k], lane holds m=c, k = kt*32 + g*8 + e ----
  short8 whA[4][10];
#pragma unroll
  for (int mt = 0; mt < 4; ++mt) {
    const int jA = w * 64 + mt * 16 + c;
#pragma unroll
    for (int kt = 0; kt < 8; ++kt)
      whA[mt][kt] = pack8(Wh + (size_t)jA * NH + kt * 32 + g * 8);
#pragma unroll
    for (int kx = 0; kx < 2; ++kx)
      whA[mt][8 + kx] = pack8(Wi + (size_t)jA * NI + kx * 32 + g * 8);
  }
  short8 woA[8];
#pragma unroll
  for (int kt = 0; kt < 8; ++kt)
    woA[kt] = pack8(Wo + (size_t)c * NH + kt * 32 + g * 8);

  f32x4 biasv[4], aprev[4], obias;
#pragma unroll
  for (int mt = 0; mt < 4; ++mt) {
#pragma unroll
    for (int r = 0; r < 4; ++r) {
      const int jD = w * 64 + mt * 16 + 4 * g + r;
      biasv[mt][r] = bi[jD] + bh[jD];
      aprev[mt][r] = h0[jD];          // hidden_init broadcast over batches
    }
  }
#pragma unroll
  for (int r = 0; r < 4; ++r) obias[r] = bo[4 * g + r];

  // ---- LDS offsets ----
  const int rd_off = ((l ^ (l >> 3)) << 4);       // read: own row l
  int wr_off[4];                                  // h-frag b64 writes
#pragma unroll
  for (int mt = 0; mt < 4; ++mt) {
    const int row = c + 16 * (2 * (mt & 1) + (g >> 1));
    wr_off[mt] = (2 * w + (mt >> 1)) * 1024 + ((row ^ (row >> 3)) << 4) + 8 * (g & 1);
  }
  const int bq = w * 4 + g;                       // x-stage: batch this thread loads
  const int q  = c;                               // i-quad
  const int rowx = bq + 16 * ((q & 7) >> 1);
  const int xw_off = (8 + (q >> 3)) * 1024 + ((rowx ^ (rowx >> 3)) << 4) + 8 * (q & 1);

  const float* xbase = x + ((size_t)(b0 + bq) * NT) * NI + q * 4;

  // ---- init frag[0]: x_0 + h0 fragments ----
  {
    f32x4 x0 = *reinterpret_cast<const f32x4*>(xbase);
    *(uint2v*)(fragc + xw_off) = packbf4(x0);
  }
  {
    const int j = tid;                     // 256 threads cover j=0..255
    const unsigned short v = f2bf(h0[j]);
    const int kt = j >> 5, gh = (j & 31) >> 3, e = j & 7;
#pragma unroll
    for (int b = 0; b < 16; ++b) {
      const int row = b + 16 * gh;
      *(unsigned short*)(fragc + kt * 1024 + ((row ^ (row >> 3)) << 4) + e * 2) = v;
    }
  }
  __syncthreads();

  f32x4 xA = *reinterpret_cast<const f32x4*>(xbase + 1 * NI);
  f32x4 xB = *reinterpret_cast<const f32x4*>(xbase + 2 * NI);

  float* rnnb[4];
#pragma unroll
  for (int mt = 0; mt < 4; ++mt)
    rnnb[mt] = rnnp + ((size_t)(b0 + c) * NT) * NH + w * 64 + mt * 16 + 4 * g;
  float* outb = outp + ((size_t)(b0 + c) * NT) * NO + 4 * g;

  auto STEP = [&](int t, int p, f32x4& xcur) {
    const char* rb = fragc + p * 10240;
    char*       wb = fragc + (p ^ 1) * 10240;

    short8 bfr[10];
#pragma unroll
    for (int kt = 0; kt < 10; ++kt)
      bfr[kt] = *(const short8*)(rb + kt * 1024 + rd_off);

    // ---- h2h + i2h: 8 chains of 5 (4 m-tiles x 2 k-halves), fp32 h+bias in C ----
    f32x4 accA[4], accB[4];
#pragma unroll
    for (int mt = 0; mt < 4; ++mt)
      accA[mt] = mfma16(whA[mt][0], bfr[0], aprev[mt] + biasv[mt]);
#pragma unroll
    for (int mt = 0; mt < 4; ++mt)
      accB[mt] = mfma16(whA[mt][5], bfr[5], cz);
#pragma unroll
    for (int kk = 1; kk < 5; ++kk) {
#pragma unroll
      for (int mt = 0; mt < 4; ++mt) {
        accA[mt] = mfma16(whA[mt][kk],     bfr[kk],     accA[mt]);
        accB[mt] = mfma16(whA[mt][5 + kk], bfr[5 + kk], accB[mt]);
      }
    }

    // ---- output projection of a_{t-1} (wave 0; fragments already read) ----
    if (w == 0) {
      f32x4 oA = mfma16(woA[0], bfr[0], cz);
      f32x4 oB = mfma16(woA[4], bfr[4], cz);
#pragma unroll
      for (int kk = 1; kk < 4; ++kk) {
        oA = mfma16(woA[kk],     bfr[kk],     oA);
        oB = mfma16(woA[4 + kk], bfr[4 + kk], oB);
      }
      if (t > 0) {
        f32x4 o = oA + oB + obias;
        *(f32x4*)(outb + (size_t)(t - 1) * NO) = o;
      }
    }

    // ---- stage x_{t+1} into wb; reload xcur <- x_{t+3} ----
    *(uint2v*)(wb + xw_off) = packbf4(xcur);
    {
      const int tl = (t + 3 < NT) ? t + 3 : NT - 1;
      xcur = *reinterpret_cast<const f32x4*>(xbase + (size_t)tl * NI);
    }

    // ---- activation, global store, h-frag write ----
#pragma unroll
    for (int mt = 0; mt < 4; ++mt) {
      f32x4 pre = accA[mt] + accB[mt];
      f32x4 a4;
#pragma unroll
      for (int r = 0; r < 4; ++r) a4[r] = fminf(fmaxf(pre[r], 0.f), 1.f);
      aprev[mt] = a4;
      *(f32x4*)(rnnb[mt] + (size_t)t * NH) = a4;
      *(uint2v*)(wb + wr_off[mt]) = packbf4(a4);
    }

    step_barrier();
  };

#pragma unroll 1
  for (int tt = 0; tt < NT; tt += 2) {
    STEP(tt,     0, xA);
    STEP(tt + 1, 1, xB);
  }

  // ---- epilogue: out[T-1] from frag[0] (holds a_{511} fragments) ----
  if (w == 0) {
    short8 bfr[8];
#pragma unroll
    for (int kt = 0; kt < 8; ++kt)
      bfr[kt] = *(const short8*)(fragc + kt * 1024 + rd_off);
    f32x4 oA = mfma16(woA[0], bfr[0], cz);
    f32x4 oB = mfma16(woA[4], bfr[4], cz);
#pragma unroll
    for (int kk = 1; kk < 4; ++kk) {
      oA = mfma16(woA[kk],     bfr[kk],     oA);
      oB = mfma16(woA[4 + kk], bfr[4 + kk], oB);
    }
    f32x4 o = oA + oB + obias;
    *(f32x4*)(outb + (size_t)(NT - 1) * NO) = o;
  }
  // ---- hidden = a_{511} (still in registers) ----
#pragma unroll
  for (int mt = 0; mt < 4; ++mt) {
    float* hb = hidp + (size_t)(b0 + c) * NH + w * 64 + mt * 16 + 4 * g;
    *(f32x4*)hb = aprev[mt];
  }
}

extern "C" void kernel_launch(void* const* d_in, const int* in_sizes, int n_in,
                              void* d_out, int out_size, void* d_ws, size_t ws_size,
                              hipStream_t stream) {
  const float* x  = (const float*)d_in[0];
  const float* Wi = (const float*)d_in[1];
  const float* bi = (const float*)d_in[2];
  const float* Wh = (const float*)d_in[3];
  const float* bh = (const float*)d_in[4];
  const float* Wo = (const float*)d_in[5];
  const float* bo = (const float*)d_in[6];
  const float* h0 = (const float*)d_in[7];
  rnn_fused<<<dim3(NBLK), dim3(256), 0, stream>>>(x, Wi, bi, Wh, bh, Wo, bo, h0,
                                                  (float*)d_out);
}